// Round 7
// baseline (430.331 us; speedup 1.0000x reference)
//
#include <hip/hip_runtime.h>
#include <hip/hip_bf16.h>

// SemWindowAttention: B=8, H=W=256, C=256, WS=8, NCLS=18
// windows = 8*32*32 = 8192, tokens/window = 64
//
// Algebraic fusion: softmax rows sum to 1 =>
//   out1 = gamma*( P @ (x @ Wf) + bf ) + x,  Wf = Wv@Wres, bf = bv@Wres + bres
//
// This round: fix the half-dirty-line HBM write blowup (r5/r6: WRITE 563->1002MB).
// Root cause: each store instr covers 64B halves of 16 cache lines; the other
// half arrived a whole LDS-bounce later -> half-open-line footprint ~ L2 size
// -> evict half-dirty -> write-allocate RMW + double writeback. Fix: pair the
// two ct tiles forming each 128B line (ct=2p,2p+1) and issue both f32x4 stores
// per token back-to-back, so every line is fully written within ~1 instr.

typedef __bf16 bf16_t;
typedef __bf16 bf16x8 __attribute__((ext_vector_type(8)));
typedef __bf16 bf16x4 __attribute__((ext_vector_type(4)));
typedef float  f32x4  __attribute__((ext_vector_type(4)));

#define MFMA16(a, b, c) __builtin_amdgcn_mfma_f32_16x16x32_bf16((a), (b), (c), 0, 0, 0)
// All inter-phase deps are through LDS; let global stores fly across barriers.
#define BAR() do { asm volatile("s_waitcnt lgkmcnt(0)" ::: "memory"); \
                   __builtin_amdgcn_s_barrier(); } while (0)

static constexpr int kC = 256, kNCLS = 18;
// ws bf16 layout (element offsets)
static constexpr int WQT_OFF = 0;        // WqT[32][256]  (n-major, zero-padded 18..31)
static constexpr int WKT_OFF = 8192;     // WkT[32][256]
static constexpr int WFT_OFF = 16384;    // WfT[256][256], WfT[n][k] = Wf[k][n]
static constexpr int BF_BYTE_OFF = 81920 * 2;  // float bf[256] after bf16 section

// XOR swizzle: byte ^= (row&7)<<4  <=>  elem ^= (row&7)<<3 (bf16). Bijective per
// row; fragment (16B) / x4 (8B) accesses keep alignment.
__device__ __forceinline__ int xs_i(int r, int c) { return (r << 8) + (c ^ ((r & 7) << 3)); }
__device__ __forceinline__ int sb_i(int r, int c) { return (r << 6) + (c ^ ((r & 7) << 3)); }

__global__ __launch_bounds__(256) void prep_kernel(
    const float* __restrict__ Wq, const float* __restrict__ Wk,
    const float* __restrict__ Wv, const float* __restrict__ bv,
    const float* __restrict__ Wres, const float* __restrict__ bres,
    bf16_t* __restrict__ wsb, float* __restrict__ bff)
{
  const int blk = blockIdx.x, t = threadIdx.x;
  if (blk < 256) {
    // WfT[n][k] = sum_j Wv[k][j] * Wres[j][n], one block per n, thread = k
    __shared__ float wcol[256];
    const int n = blk;
    wcol[t] = Wres[t * kC + n];
    __syncthreads();
    float acc = 0.f;
    const float* wvrow = Wv + (size_t)t * kC;
#pragma unroll 4
    for (int j = 0; j < 256; j += 4) {
      f32x4 a = *(const f32x4*)(wvrow + j);
      acc += a[0] * wcol[j] + a[1] * wcol[j + 1] + a[2] * wcol[j + 2] + a[3] * wcol[j + 3];
    }
    wsb[WFT_OFF + n * kC + t] = (bf16_t)acc;
  } else if (blk == 256) {
    // bf[n] = sum_j bv[j]*Wres[j][n] + bres[n]
    float acc = bres[t];
    for (int j = 0; j < 256; ++j) acc += bv[j] * Wres[j * kC + t];
    bff[t] = acc;
  } else {
    int tid = (blk - 257) * 256 + t;  // 0..16383
    if (tid < 8192) {
      int n = tid >> 8, k = tid & 255;
      wsb[WQT_OFF + tid] = (n < kNCLS) ? (bf16_t)Wq[k * kNCLS + n] : (bf16_t)0.0f;
    } else {
      int u = tid - 8192;
      int n = u >> 8, k = u & 255;
      wsb[WKT_OFF + u] = (n < kNCLS) ? (bf16_t)Wk[k * kNCLS + n] : (bf16_t)0.0f;
    }
  }
}

__global__ __launch_bounds__(256, 4) void semwin_main(
    const float* __restrict__ x,
    const float* __restrict__ bq, const float* __restrict__ bk,
    const float* __restrict__ gamma,
    const bf16_t* __restrict__ wsb, const float* __restrict__ bff,
    float* __restrict__ out0, float* __restrict__ out1)
{
  // LDS: 32768 + 8192 = 40960 B exactly -> 4 wg/CU (163840/4)
  __shared__ bf16_t xsf[64 * 256];  // x window bf16, XOR-swizzled rows
  __shared__ bf16_t sbf[64 * 64];   // QK[64][0:32|32:64] -> Ps[64][64] -> per-wave Utc

  const int tid  = threadIdx.x;
  const int wave = tid >> 6;
  const int lane = tid & 63;
  const int l15  = lane & 15;
  const int g    = lane >> 4;

  const int wid = blockIdx.x;
  const int b   = wid >> 10;
  const int wh  = (wid >> 5) & 31;
  const int ww  = wid & 31;
  const int pixbase = (b << 16) + (wh << 11) + (ww << 3);
  // pixel(t) = pixbase + (t>>3)*256 + (t&7)

  const f32x4 fzero = {0.f, 0.f, 0.f, 0.f};
  const float gm = gamma[0];

  // ---- stage x window -> xs (bf16, swizzled) ----
  {
    const int t = tid >> 2;
    const int q = tid & 3;
    const float* src = x + (size_t)(pixbase + ((t >> 3) << 8) + (t & 7)) * kC + q * 8;
#pragma unroll
    for (int i = 0; i < 8; ++i) {
      f32x4 a = *(const f32x4*)(src + i * 32);
      f32x4 c = *(const f32x4*)(src + i * 32 + 4);
      bf16x8 v;
      v[0] = (bf16_t)a[0]; v[1] = (bf16_t)a[1]; v[2] = (bf16_t)a[2]; v[3] = (bf16_t)a[3];
      v[4] = (bf16_t)c[0]; v[5] = (bf16_t)c[1]; v[6] = (bf16_t)c[2]; v[7] = (bf16_t)c[3];
      *(bf16x8*)&xsf[xs_i(t, i * 32 + q * 8)] = v;
    }
  }
  BAR();

  // ---- phase A: Q = xw@Wq + bq (waves 0,1); K = xw@Wk + bk (waves 2,3) ----
  // QK buffer: rows = tokens, cols 0..31 = Q (padded), cols 32..63 = K.
  {
    const bf16_t* wt   = wsb + ((wave < 2) ? WQT_OFF : WKT_OFF);
    const float*  bias = (wave < 2) ? bq : bk;
    const int mbase = (wave & 1) << 5;  // rows 0..31 or 32..63
    const int cofs  = (wave < 2) ? 0 : 32;
    f32x4 acc[2][2];
#pragma unroll
    for (int mt = 0; mt < 2; ++mt)
#pragma unroll
      for (int nt = 0; nt < 2; ++nt) acc[mt][nt] = fzero;
#pragma unroll
    for (int k0 = 0; k0 < 256; k0 += 32) {
      bf16x8 a0 = *(const bf16x8*)&xsf[xs_i(mbase + l15, k0 + g * 8)];
      bf16x8 a1 = *(const bf16x8*)&xsf[xs_i(mbase + 16 + l15, k0 + g * 8)];
      bf16x8 b0 = *(const bf16x8*)(wt + l15 * 256 + k0 + g * 8);
      bf16x8 b1 = *(const bf16x8*)(wt + (16 + l15) * 256 + k0 + g * 8);
      acc[0][0] = MFMA16(a0, b0, acc[0][0]);
      acc[0][1] = MFMA16(a0, b1, acc[0][1]);
      acc[1][0] = MFMA16(a1, b0, acc[1][0]);
      acc[1][1] = MFMA16(a1, b1, acc[1][1]);
    }
    const bool isQ = (wave < 2);
#pragma unroll
    for (int nt = 0; nt < 2; ++nt) {
      const int coln = (nt << 4) + l15;
      const float bval = (coln < kNCLS) ? bias[coln] : 0.f;
#pragma unroll
      for (int mt = 0; mt < 2; ++mt) {
#pragma unroll
        for (int r = 0; r < 4; ++r) {
          const int row = mbase + (mt << 4) + (g << 2) + r;  // token
          const float v = acc[mt][nt][r] + bval;
          sbf[sb_i(row, cofs + coln)] = (bf16_t)v;
          if (isQ && coln < kNCLS) {
            out0[(size_t)(pixbase + ((row >> 3) << 8) + (row & 7)) * kNCLS + coln] = v;
          }
        }
      }
    }
  }
  BAR();

  // ---- phase S: S = Q K^T (64x64, K=32 padded), in-register softmax -> Ps ----
  {
    const int mbase = wave << 4;
    const bf16x8 aq = *(const bf16x8*)&sbf[sb_i(mbase + l15, g * 8)];
    f32x4 s[4];
#pragma unroll
    for (int nt = 0; nt < 4; ++nt) {
      bf16x8 bk8 = *(const bf16x8*)&sbf[sb_i((nt << 4) + l15, 32 + g * 8)];
      s[nt] = MFMA16(aq, bk8, fzero);
    }
    BAR();  // all waves done reading Q/K (Ps aliases them)
#pragma unroll
    for (int r = 0; r < 4; ++r) {
      float m = fmaxf(fmaxf(s[0][r], s[1][r]), fmaxf(s[2][r], s[3][r]));
#pragma unroll
      for (int off = 1; off < 16; off <<= 1) m = fmaxf(m, __shfl_xor(m, off));
      float e0 = __expf(s[0][r] - m), e1 = __expf(s[1][r] - m);
      float e2 = __expf(s[2][r] - m), e3 = __expf(s[3][r] - m);
      float sum = (e0 + e1) + (e2 + e3);
#pragma unroll
      for (int off = 1; off < 16; off <<= 1) sum += __shfl_xor(sum, off);
      const float inv = 1.0f / sum;
      const int row = mbase + (g << 2) + r;
      sbf[sb_i(row, l15)]      = (bf16_t)(e0 * inv);
      sbf[sb_i(row, 16 + l15)] = (bf16_t)(e1 * inv);
      sbf[sb_i(row, 32 + l15)] = (bf16_t)(e2 * inv);
      sbf[sb_i(row, 48 + l15)] = (bf16_t)(e3 * inv);
    }
  }
  BAR();  // P visible to all waves

  // ---- hoist P fragments to registers ----
  bf16x8 bp[4][2];
#pragma unroll
  for (int nt = 0; nt < 4; ++nt) {
    bp[nt][0] = *(const bf16x8*)&sbf[sb_i((nt << 4) + l15, g * 8)];
    bp[nt][1] = *(const bf16x8*)&sbf[sb_i((nt << 4) + l15, 32 + g * 8)];
  }
  BAR();  // Ps reads done before Utc (same buffer) is overwritten
  // ======== NO MORE BARRIERS BELOW: remaining work is intra-wave only ========
  // Wave w owns out1 channels [w*64,(w+1)*64) = cache lines 2w,2w+1 of every
  // token row. Private Utc slice = sbf rows [w*16,w*16+16).

  // ---- single U sweep: U^T[w*64..w*64+64)[all 64 tokens] ----
  f32x4 accU[4][4];  // [ct][mt] : ct = channel tile, mt = token tile
#pragma unroll
  for (int ct = 0; ct < 4; ++ct)
#pragma unroll
    for (int mt = 0; mt < 4; ++mt) accU[ct][mt] = fzero;
  {
    const bf16_t* wftw = wsb + WFT_OFF + (size_t)((wave << 6) + l15) * 256;
#pragma unroll
    for (int k0 = 0; k0 < 256; k0 += 32) {
      bf16x8 af0 = *(const bf16x8*)&xsf[xs_i(l15, k0 + g * 8)];
      bf16x8 af1 = *(const bf16x8*)&xsf[xs_i(16 + l15, k0 + g * 8)];
      bf16x8 af2 = *(const bf16x8*)&xsf[xs_i(32 + l15, k0 + g * 8)];
      bf16x8 af3 = *(const bf16x8*)&xsf[xs_i(48 + l15, k0 + g * 8)];
#pragma unroll
      for (int ct = 0; ct < 4; ++ct) {
        bf16x8 bf = *(const bf16x8*)(wftw + ct * 16 * 256 + k0 + g * 8);
        accU[ct][0] = MFMA16(af0, bf, accU[ct][0]);
        accU[ct][1] = MFMA16(af1, bf, accU[ct][1]);
        accU[ct][2] = MFMA16(af2, bf, accU[ct][2]);
        accU[ct][3] = MFMA16(af3, bf, accU[ct][3]);
      }
    }
  }

  // ---- per line-pair p: bounce BOTH ct tiles, then store full 128B lines ----
  // Line 2w+p = channels [w*64+p*32, w*64+p*32+32) = ct tiles {2p, 2p+1}.
#pragma unroll
  for (int p = 0; p < 2; ++p) {
    bf16x8 av[2][2];  // [ctl][khalf]
#pragma unroll
    for (int ctl = 0; ctl < 2; ++ctl) {
      const int ct = (p << 1) + ctl;
      // write private Utc slice (compiler orders vs prior reads via lgkmcnt)
#pragma unroll
      for (int mt = 0; mt < 4; ++mt) {
        bf16x4 pk;
#pragma unroll
        for (int r = 0; r < 4; ++r) pk[r] = (bf16_t)accU[ct][mt][r];
        *(bf16x4*)&sbf[sb_i((wave << 4) + l15, (mt << 4) + (g << 2))] = pk;
      }
      av[ctl][0] = *(const bf16x8*)&sbf[sb_i((wave << 4) + l15, g * 8)];
      av[ctl][1] = *(const bf16x8*)&sbf[sb_i((wave << 4) + l15, 32 + g * 8)];
    }
    const int c2 = (wave << 6) + (p << 5) + (g << 2);  // ctl=0 chans
    const f32x4 bfv0 = *(const f32x4*)(bff + c2);
    const f32x4 bfv1 = *(const f32x4*)(bff + c2 + 16);
#pragma unroll
    for (int nt = 0; nt < 4; ++nt) {
      f32x4 a0 = MFMA16(av[0][0], bp[nt][0], fzero);
      a0 = MFMA16(av[0][1], bp[nt][1], a0);
      f32x4 a1 = MFMA16(av[1][0], bp[nt][0], fzero);
      a1 = MFMA16(av[1][1], bp[nt][1], a1);
      const int t = (nt << 4) + l15;
      const bf16x4 xv0 = *(const bf16x4*)&xsf[xs_i(t, c2)];
      const bf16x4 xv1 = *(const bf16x4*)&xsf[xs_i(t, c2 + 16)];
      f32x4 o0, o1;
#pragma unroll
      for (int r = 0; r < 4; ++r) {
        o0[r] = gm * (a0[r] + bfv0[r]) + (float)xv0[r];
        o1[r] = gm * (a1[r] + bfv1[r]) + (float)xv1[r];
      }
      float* dst = out1 + (size_t)(pixbase + ((t >> 3) << 8) + (t & 7)) * kC + c2;
      *(f32x4*)dst = o0;          // bytes [g*16, g*16+16) of line half 0
      *(f32x4*)(dst + 16) = o1;   // bytes [64+g*16, ...) — full 128B line
    }                             // completed back-to-back per token
  }
}

extern "C" void kernel_launch(void* const* d_in, const int* in_sizes, int n_in,
                              void* d_out, int out_size, void* d_ws, size_t ws_size,
                              hipStream_t stream)
{
  const float* x     = (const float*)d_in[0];
  const float* Wq    = (const float*)d_in[1];
  const float* bq    = (const float*)d_in[2];
  const float* Wk    = (const float*)d_in[3];
  const float* bk    = (const float*)d_in[4];
  const float* Wv    = (const float*)d_in[5];
  const float* bv    = (const float*)d_in[6];
  const float* Wres  = (const float*)d_in[7];
  const float* bres  = (const float*)d_in[8];
  const float* gamma = (const float*)d_in[9];
  bf16_t* wsb = (bf16_t*)d_ws;                         // 81920 bf16 = 163840 B
  float*  bff = (float*)((char*)d_ws + BF_BYTE_OFF);   // + 1024 B
  float* out0 = (float*)d_out;                         // (8,256,256,18)
  float* out1 = out0 + (size_t)8 * 256 * 256 * 18;     // (8,256,256,256)

  prep_kernel<<<dim3(321), dim3(256), 0, stream>>>(Wq, Wk, Wv, bv, Wres, bres, wsb, bff);
  semwin_main<<<dim3(8192), dim3(256), 0, stream>>>(x, bq, bk, gamma, wsb, bff, out0, out1);
}

// Round 8
// 372.474 us; speedup vs baseline: 1.1553x; 1.1553x over previous
//
#include <hip/hip_runtime.h>
#include <hip/hip_bf16.h>

// SemWindowAttention: B=8, H=W=256, C=256, WS=8, NCLS=18
// windows = 8*32*32 = 8192, tokens/window = 64
//
// Algebraic fusion: softmax rows sum to 1 =>
//   out1 = gamma*( P @ (x @ Wf) + bf ) + x,  Wf = Wv@Wres, bf = bv@Wres + bres
//
// This round: kill the register spill. R6/R7's accU[4][4] (64 f32) + bp (32)
// + av (16) exceeded the 128-reg cap of launch_bounds(256,4) -> scratch
// spill -> ~+400MB HBM write + ~+200MB fetch (spill traffic, not line RMW:
// R7 proved line-complete adjacent stores don't reduce it). Fix: 2 passes
// with accU[2][4] (32 regs), peak live ~100 regs, zero scratch. Store layout
// keeps wave-owned 64-ch block + line-complete o0/o1 pairs.

typedef __bf16 bf16_t;
typedef __bf16 bf16x8 __attribute__((ext_vector_type(8)));
typedef __bf16 bf16x4 __attribute__((ext_vector_type(4)));
typedef float  f32x4  __attribute__((ext_vector_type(4)));

#define MFMA16(a, b, c) __builtin_amdgcn_mfma_f32_16x16x32_bf16((a), (b), (c), 0, 0, 0)
// All inter-phase deps are through LDS; let global stores fly across barriers.
#define BAR() do { asm volatile("s_waitcnt lgkmcnt(0)" ::: "memory"); \
                   __builtin_amdgcn_s_barrier(); } while (0)

static constexpr int kC = 256, kNCLS = 18;
// ws bf16 layout (element offsets)
static constexpr int WQT_OFF = 0;        // WqT[32][256]  (n-major, zero-padded 18..31)
static constexpr int WKT_OFF = 8192;     // WkT[32][256]
static constexpr int WFT_OFF = 16384;    // WfT[256][256], WfT[n][k] = Wf[k][n]
static constexpr int BF_BYTE_OFF = 81920 * 2;  // float bf[256] after bf16 section

// XOR swizzle: byte ^= (row&7)<<4  <=>  elem ^= (row&7)<<3 (bf16). Bijective per
// row; fragment (16B) / x4 (8B) accesses keep alignment.
__device__ __forceinline__ int xs_i(int r, int c) { return (r << 8) + (c ^ ((r & 7) << 3)); }
__device__ __forceinline__ int sb_i(int r, int c) { return (r << 6) + (c ^ ((r & 7) << 3)); }

__global__ __launch_bounds__(256) void prep_kernel(
    const float* __restrict__ Wq, const float* __restrict__ Wk,
    const float* __restrict__ Wv, const float* __restrict__ bv,
    const float* __restrict__ Wres, const float* __restrict__ bres,
    bf16_t* __restrict__ wsb, float* __restrict__ bff)
{
  const int blk = blockIdx.x, t = threadIdx.x;
  if (blk < 256) {
    // WfT[n][k] = sum_j Wv[k][j] * Wres[j][n], one block per n, thread = k
    __shared__ float wcol[256];
    const int n = blk;
    wcol[t] = Wres[t * kC + n];
    __syncthreads();
    float acc = 0.f;
    const float* wvrow = Wv + (size_t)t * kC;
#pragma unroll 4
    for (int j = 0; j < 256; j += 4) {
      f32x4 a = *(const f32x4*)(wvrow + j);
      acc += a[0] * wcol[j] + a[1] * wcol[j + 1] + a[2] * wcol[j + 2] + a[3] * wcol[j + 3];
    }
    wsb[WFT_OFF + n * kC + t] = (bf16_t)acc;
  } else if (blk == 256) {
    // bf[n] = sum_j bv[j]*Wres[j][n] + bres[n]
    float acc = bres[t];
    for (int j = 0; j < 256; ++j) acc += bv[j] * Wres[j * kC + t];
    bff[t] = acc;
  } else {
    int tid = (blk - 257) * 256 + t;  // 0..16383
    if (tid < 8192) {
      int n = tid >> 8, k = tid & 255;
      wsb[WQT_OFF + tid] = (n < kNCLS) ? (bf16_t)Wq[k * kNCLS + n] : (bf16_t)0.0f;
    } else {
      int u = tid - 8192;
      int n = u >> 8, k = u & 255;
      wsb[WKT_OFF + u] = (n < kNCLS) ? (bf16_t)Wk[k * kNCLS + n] : (bf16_t)0.0f;
    }
  }
}

__global__ __launch_bounds__(256, 4) void semwin_main(
    const float* __restrict__ x,
    const float* __restrict__ bq, const float* __restrict__ bk,
    const float* __restrict__ gamma,
    const bf16_t* __restrict__ wsb, const float* __restrict__ bff,
    float* __restrict__ out0, float* __restrict__ out1)
{
  // LDS: 32768 + 8192 = 40960 B exactly -> 4 wg/CU (163840/4)
  __shared__ bf16_t xsf[64 * 256];  // x window bf16, XOR-swizzled rows
  __shared__ bf16_t sbf[64 * 64];   // QK[64][0:32|32:64] -> Ps[64][64] -> per-wave Utc

  const int tid  = threadIdx.x;
  const int wave = tid >> 6;
  const int lane = tid & 63;
  const int l15  = lane & 15;
  const int g    = lane >> 4;

  const int wid = blockIdx.x;
  const int b   = wid >> 10;
  const int wh  = (wid >> 5) & 31;
  const int ww  = wid & 31;
  const int pixbase = (b << 16) + (wh << 11) + (ww << 3);
  // pixel(t) = pixbase + (t>>3)*256 + (t&7)

  const f32x4 fzero = {0.f, 0.f, 0.f, 0.f};
  const float gm = gamma[0];

  // ---- stage x window -> xs (bf16, swizzled) ----
  {
    const int t = tid >> 2;
    const int q = tid & 3;
    const float* src = x + (size_t)(pixbase + ((t >> 3) << 8) + (t & 7)) * kC + q * 8;
#pragma unroll
    for (int i = 0; i < 8; ++i) {
      f32x4 a = *(const f32x4*)(src + i * 32);
      f32x4 c = *(const f32x4*)(src + i * 32 + 4);
      bf16x8 v;
      v[0] = (bf16_t)a[0]; v[1] = (bf16_t)a[1]; v[2] = (bf16_t)a[2]; v[3] = (bf16_t)a[3];
      v[4] = (bf16_t)c[0]; v[5] = (bf16_t)c[1]; v[6] = (bf16_t)c[2]; v[7] = (bf16_t)c[3];
      *(bf16x8*)&xsf[xs_i(t, i * 32 + q * 8)] = v;
    }
  }
  BAR();

  // ---- phase A: Q = xw@Wq + bq (waves 0,1); K = xw@Wk + bk (waves 2,3) ----
  // QK buffer: rows = tokens, cols 0..31 = Q (padded), cols 32..63 = K.
  {
    const bf16_t* wt   = wsb + ((wave < 2) ? WQT_OFF : WKT_OFF);
    const float*  bias = (wave < 2) ? bq : bk;
    const int mbase = (wave & 1) << 5;  // rows 0..31 or 32..63
    const int cofs  = (wave < 2) ? 0 : 32;
    f32x4 acc[2][2];
#pragma unroll
    for (int mt = 0; mt < 2; ++mt)
#pragma unroll
      for (int nt = 0; nt < 2; ++nt) acc[mt][nt] = fzero;
#pragma unroll
    for (int k0 = 0; k0 < 256; k0 += 32) {
      bf16x8 a0 = *(const bf16x8*)&xsf[xs_i(mbase + l15, k0 + g * 8)];
      bf16x8 a1 = *(const bf16x8*)&xsf[xs_i(mbase + 16 + l15, k0 + g * 8)];
      bf16x8 b0 = *(const bf16x8*)(wt + l15 * 256 + k0 + g * 8);
      bf16x8 b1 = *(const bf16x8*)(wt + (16 + l15) * 256 + k0 + g * 8);
      acc[0][0] = MFMA16(a0, b0, acc[0][0]);
      acc[0][1] = MFMA16(a0, b1, acc[0][1]);
      acc[1][0] = MFMA16(a1, b0, acc[1][0]);
      acc[1][1] = MFMA16(a1, b1, acc[1][1]);
    }
    const bool isQ = (wave < 2);
#pragma unroll
    for (int nt = 0; nt < 2; ++nt) {
      const int coln = (nt << 4) + l15;
      const float bval = (coln < kNCLS) ? bias[coln] : 0.f;
#pragma unroll
      for (int mt = 0; mt < 2; ++mt) {
#pragma unroll
        for (int r = 0; r < 4; ++r) {
          const int row = mbase + (mt << 4) + (g << 2) + r;  // token
          const float v = acc[mt][nt][r] + bval;
          sbf[sb_i(row, cofs + coln)] = (bf16_t)v;
          if (isQ && coln < kNCLS) {
            out0[(size_t)(pixbase + ((row >> 3) << 8) + (row & 7)) * kNCLS + coln] = v;
          }
        }
      }
    }
  }
  BAR();

  // ---- phase S: S = Q K^T (64x64, K=32 padded), in-register softmax -> Ps ----
  {
    const int mbase = wave << 4;
    const bf16x8 aq = *(const bf16x8*)&sbf[sb_i(mbase + l15, g * 8)];
    f32x4 s[4];
#pragma unroll
    for (int nt = 0; nt < 4; ++nt) {
      bf16x8 bk8 = *(const bf16x8*)&sbf[sb_i((nt << 4) + l15, 32 + g * 8)];
      s[nt] = MFMA16(aq, bk8, fzero);
    }
    BAR();  // all waves done reading Q/K (Ps aliases them)
#pragma unroll
    for (int r = 0; r < 4; ++r) {
      float m = fmaxf(fmaxf(s[0][r], s[1][r]), fmaxf(s[2][r], s[3][r]));
#pragma unroll
      for (int off = 1; off < 16; off <<= 1) m = fmaxf(m, __shfl_xor(m, off));
      float e0 = __expf(s[0][r] - m), e1 = __expf(s[1][r] - m);
      float e2 = __expf(s[2][r] - m), e3 = __expf(s[3][r] - m);
      float sum = (e0 + e1) + (e2 + e3);
#pragma unroll
      for (int off = 1; off < 16; off <<= 1) sum += __shfl_xor(sum, off);
      const float inv = 1.0f / sum;
      const int row = mbase + (g << 2) + r;
      sbf[sb_i(row, l15)]      = (bf16_t)(e0 * inv);
      sbf[sb_i(row, 16 + l15)] = (bf16_t)(e1 * inv);
      sbf[sb_i(row, 32 + l15)] = (bf16_t)(e2 * inv);
      sbf[sb_i(row, 48 + l15)] = (bf16_t)(e3 * inv);
    }
  }
  BAR();  // P visible to all waves

  // ---- hoist P fragments to registers ----
  bf16x8 bp[4][2];
#pragma unroll
  for (int nt = 0; nt < 4; ++nt) {
    bp[nt][0] = *(const bf16x8*)&sbf[sb_i((nt << 4) + l15, g * 8)];
    bp[nt][1] = *(const bf16x8*)&sbf[sb_i((nt << 4) + l15, 32 + g * 8)];
  }
  BAR();  // Ps reads done before Utc (same buffer) is overwritten
  // ======== NO MORE BARRIERS BELOW: remaining work is intra-wave only ========
  // Wave w owns out1 channels [w*64,(w+1)*64) = cache lines 2w,2w+1 of every
  // token row. Private Utc slice = sbf rows [w*16,w*16+16).
  // Pass p handles line p (32 ch = ct tiles {2p,2p+1}) with accU[2][4] only
  // (32 f32 regs) -> peak live ~100 regs, no scratch spill.

#pragma unroll
  for (int p = 0; p < 2; ++p) {
    // ---- U sweep for this line: U^T[w*64+p*32 .. +32)[all 64 tokens] ----
    f32x4 accU[2][4];  // [ctl][mt]
#pragma unroll
    for (int ctl = 0; ctl < 2; ++ctl)
#pragma unroll
      for (int mt = 0; mt < 4; ++mt) accU[ctl][mt] = fzero;
    {
      const bf16_t* wftp = wsb + WFT_OFF + (size_t)((wave << 6) + (p << 5) + l15) * 256;
#pragma unroll
      for (int k0 = 0; k0 < 256; k0 += 32) {
        bf16x8 af0 = *(const bf16x8*)&xsf[xs_i(l15, k0 + g * 8)];
        bf16x8 af1 = *(const bf16x8*)&xsf[xs_i(16 + l15, k0 + g * 8)];
        bf16x8 af2 = *(const bf16x8*)&xsf[xs_i(32 + l15, k0 + g * 8)];
        bf16x8 af3 = *(const bf16x8*)&xsf[xs_i(48 + l15, k0 + g * 8)];
        bf16x8 bf0 = *(const bf16x8*)(wftp + k0 + g * 8);
        bf16x8 bf1 = *(const bf16x8*)(wftp + 16 * 256 + k0 + g * 8);
        accU[0][0] = MFMA16(af0, bf0, accU[0][0]);
        accU[0][1] = MFMA16(af1, bf0, accU[0][1]);
        accU[0][2] = MFMA16(af2, bf0, accU[0][2]);
        accU[0][3] = MFMA16(af3, bf0, accU[0][3]);
        accU[1][0] = MFMA16(af0, bf1, accU[1][0]);
        accU[1][1] = MFMA16(af1, bf1, accU[1][1]);
        accU[1][2] = MFMA16(af2, bf1, accU[1][2]);
        accU[1][3] = MFMA16(af3, bf1, accU[1][3]);
      }
    }

    // ---- bounce both ct tiles through private slice -> A-frags ----
    bf16x8 av[2][2];  // [ctl][khalf]
#pragma unroll
    for (int ctl = 0; ctl < 2; ++ctl) {
#pragma unroll
      for (int mt = 0; mt < 4; ++mt) {
        bf16x4 pk;
#pragma unroll
        for (int r = 0; r < 4; ++r) pk[r] = (bf16_t)accU[ctl][mt][r];
        *(bf16x4*)&sbf[sb_i((wave << 4) + l15, (mt << 4) + (g << 2))] = pk;
      }
      av[ctl][0] = *(const bf16x8*)&sbf[sb_i((wave << 4) + l15, g * 8)];
      av[ctl][1] = *(const bf16x8*)&sbf[sb_i((wave << 4) + l15, 32 + g * 8)];
    }

    // ---- PV + fused epilogue, line-complete o0/o1 store pairs ----
    const int c2 = (wave << 6) + (p << 5) + (g << 2);
    const f32x4 bfv0 = *(const f32x4*)(bff + c2);
    const f32x4 bfv1 = *(const f32x4*)(bff + c2 + 16);
#pragma unroll
    for (int nt = 0; nt < 4; ++nt) {
      f32x4 a0 = MFMA16(av[0][0], bp[nt][0], fzero);
      a0 = MFMA16(av[0][1], bp[nt][1], a0);
      f32x4 a1 = MFMA16(av[1][0], bp[nt][0], fzero);
      a1 = MFMA16(av[1][1], bp[nt][1], a1);
      const int t = (nt << 4) + l15;
      const bf16x4 xv0 = *(const bf16x4*)&xsf[xs_i(t, c2)];
      const bf16x4 xv1 = *(const bf16x4*)&xsf[xs_i(t, c2 + 16)];
      f32x4 o0, o1;
#pragma unroll
      for (int r = 0; r < 4; ++r) {
        o0[r] = gm * (a0[r] + bfv0[r]) + (float)xv0[r];
        o1[r] = gm * (a1[r] + bfv1[r]) + (float)xv1[r];
      }
      float* dst = out1 + (size_t)(pixbase + ((t >> 3) << 8) + (t & 7)) * kC + c2;
      *(f32x4*)dst = o0;          // bytes [g*16, g*16+16) of line half 0
      *(f32x4*)(dst + 16) = o1;   // bytes [64+g*16, ...) — full 128B line
    }
  }
}

extern "C" void kernel_launch(void* const* d_in, const int* in_sizes, int n_in,
                              void* d_out, int out_size, void* d_ws, size_t ws_size,
                              hipStream_t stream)
{
  const float* x     = (const float*)d_in[0];
  const float* Wq    = (const float*)d_in[1];
  const float* bq    = (const float*)d_in[2];
  const float* Wk    = (const float*)d_in[3];
  const float* bk    = (const float*)d_in[4];
  const float* Wv    = (const float*)d_in[5];
  const float* bv    = (const float*)d_in[6];
  const float* Wres  = (const float*)d_in[7];
  const float* bres  = (const float*)d_in[8];
  const float* gamma = (const float*)d_in[9];
  bf16_t* wsb = (bf16_t*)d_ws;                         // 81920 bf16 = 163840 B
  float*  bff = (float*)((char*)d_ws + BF_BYTE_OFF);   // + 1024 B
  float* out0 = (float*)d_out;                         // (8,256,256,18)
  float* out1 = out0 + (size_t)8 * 256 * 256 * 18;     // (8,256,256,256)

  prep_kernel<<<dim3(321), dim3(256), 0, stream>>>(Wq, Wk, Wv, bv, Wres, bres, wsb, bff);
  semwin_main<<<dim3(8192), dim3(256), 0, stream>>>(x, bq, bk, gamma, wsb, bff, out0, out1);
}

// Round 9
// 329.845 us; speedup vs baseline: 1.3046x; 1.1292x over previous
//
#include <hip/hip_runtime.h>
#include <hip/hip_bf16.h>

// SemWindowAttention: B=8, H=W=256, C=256, WS=8, NCLS=18
// windows = 8*32*32 = 8192, tokens/window = 64
//
// Algebraic fusion: softmax rows sum to 1 =>
//   out1 = gamma*( P @ (x @ Wf) + bf ) + x,  Wf = Wv@Wres, bf = bv@Wres + bres
//
// This round: restore a barriered store cadence in the tail. Empirical
// invariant across R4..R8: barrier-synced tails give clean HBM traffic
// (563W/264F); barrier-free tails leak (+165W/+82F even with line-complete
// single-wave stores and no spill). Add rendezvous-only lgkm BARs (after each
// U-sweep, after each pass's stores) to bound wave drift to ~half a pass.

typedef __bf16 bf16_t;
typedef __bf16 bf16x8 __attribute__((ext_vector_type(8)));
typedef __bf16 bf16x4 __attribute__((ext_vector_type(4)));
typedef float  f32x4  __attribute__((ext_vector_type(4)));

#define MFMA16(a, b, c) __builtin_amdgcn_mfma_f32_16x16x32_bf16((a), (b), (c), 0, 0, 0)
// All inter-phase deps are through LDS; let global stores fly across barriers.
#define BAR() do { asm volatile("s_waitcnt lgkmcnt(0)" ::: "memory"); \
                   __builtin_amdgcn_s_barrier(); } while (0)

static constexpr int kC = 256, kNCLS = 18;
// ws bf16 layout (element offsets)
static constexpr int WQT_OFF = 0;        // WqT[32][256]  (n-major, zero-padded 18..31)
static constexpr int WKT_OFF = 8192;     // WkT[32][256]
static constexpr int WFT_OFF = 16384;    // WfT[256][256], WfT[n][k] = Wf[k][n]
static constexpr int BF_BYTE_OFF = 81920 * 2;  // float bf[256] after bf16 section

// XOR swizzle: byte ^= (row&7)<<4  <=>  elem ^= (row&7)<<3 (bf16). Bijective per
// row; fragment (16B) / x4 (8B) accesses keep alignment.
__device__ __forceinline__ int xs_i(int r, int c) { return (r << 8) + (c ^ ((r & 7) << 3)); }
__device__ __forceinline__ int sb_i(int r, int c) { return (r << 6) + (c ^ ((r & 7) << 3)); }

__global__ __launch_bounds__(256) void prep_kernel(
    const float* __restrict__ Wq, const float* __restrict__ Wk,
    const float* __restrict__ Wv, const float* __restrict__ bv,
    const float* __restrict__ Wres, const float* __restrict__ bres,
    bf16_t* __restrict__ wsb, float* __restrict__ bff)
{
  const int blk = blockIdx.x, t = threadIdx.x;
  if (blk < 256) {
    // WfT[n][k] = sum_j Wv[k][j] * Wres[j][n], one block per n, thread = k
    __shared__ float wcol[256];
    const int n = blk;
    wcol[t] = Wres[t * kC + n];
    __syncthreads();
    float acc = 0.f;
    const float* wvrow = Wv + (size_t)t * kC;
#pragma unroll 4
    for (int j = 0; j < 256; j += 4) {
      f32x4 a = *(const f32x4*)(wvrow + j);
      acc += a[0] * wcol[j] + a[1] * wcol[j + 1] + a[2] * wcol[j + 2] + a[3] * wcol[j + 3];
    }
    wsb[WFT_OFF + n * kC + t] = (bf16_t)acc;
  } else if (blk == 256) {
    // bf[n] = sum_j bv[j]*Wres[j][n] + bres[n]
    float acc = bres[t];
    for (int j = 0; j < 256; ++j) acc += bv[j] * Wres[j * kC + t];
    bff[t] = acc;
  } else {
    int tid = (blk - 257) * 256 + t;  // 0..16383
    if (tid < 8192) {
      int n = tid >> 8, k = tid & 255;
      wsb[WQT_OFF + tid] = (n < kNCLS) ? (bf16_t)Wq[k * kNCLS + n] : (bf16_t)0.0f;
    } else {
      int u = tid - 8192;
      int n = u >> 8, k = u & 255;
      wsb[WKT_OFF + u] = (n < kNCLS) ? (bf16_t)Wk[k * kNCLS + n] : (bf16_t)0.0f;
    }
  }
}

__global__ __launch_bounds__(256, 4) void semwin_main(
    const float* __restrict__ x,
    const float* __restrict__ bq, const float* __restrict__ bk,
    const float* __restrict__ gamma,
    const bf16_t* __restrict__ wsb, const float* __restrict__ bff,
    float* __restrict__ out0, float* __restrict__ out1)
{
  // LDS: 32768 + 8192 = 40960 B exactly -> 4 wg/CU (163840/4)
  __shared__ bf16_t xsf[64 * 256];  // x window bf16, XOR-swizzled rows
  __shared__ bf16_t sbf[64 * 64];   // QK[64][0:32|32:64] -> Ps[64][64] -> per-wave Utc

  const int tid  = threadIdx.x;
  const int wave = tid >> 6;
  const int lane = tid & 63;
  const int l15  = lane & 15;
  const int g    = lane >> 4;

  const int wid = blockIdx.x;
  const int b   = wid >> 10;
  const int wh  = (wid >> 5) & 31;
  const int ww  = wid & 31;
  const int pixbase = (b << 16) + (wh << 11) + (ww << 3);
  // pixel(t) = pixbase + (t>>3)*256 + (t&7)

  const f32x4 fzero = {0.f, 0.f, 0.f, 0.f};
  const float gm = gamma[0];

  // ---- stage x window -> xs (bf16, swizzled) ----
  {
    const int t = tid >> 2;
    const int q = tid & 3;
    const float* src = x + (size_t)(pixbase + ((t >> 3) << 8) + (t & 7)) * kC + q * 8;
#pragma unroll
    for (int i = 0; i < 8; ++i) {
      f32x4 a = *(const f32x4*)(src + i * 32);
      f32x4 c = *(const f32x4*)(src + i * 32 + 4);
      bf16x8 v;
      v[0] = (bf16_t)a[0]; v[1] = (bf16_t)a[1]; v[2] = (bf16_t)a[2]; v[3] = (bf16_t)a[3];
      v[4] = (bf16_t)c[0]; v[5] = (bf16_t)c[1]; v[6] = (bf16_t)c[2]; v[7] = (bf16_t)c[3];
      *(bf16x8*)&xsf[xs_i(t, i * 32 + q * 8)] = v;
    }
  }
  BAR();

  // ---- phase A: Q = xw@Wq + bq (waves 0,1); K = xw@Wk + bk (waves 2,3) ----
  // QK buffer: rows = tokens, cols 0..31 = Q (padded), cols 32..63 = K.
  {
    const bf16_t* wt   = wsb + ((wave < 2) ? WQT_OFF : WKT_OFF);
    const float*  bias = (wave < 2) ? bq : bk;
    const int mbase = (wave & 1) << 5;  // rows 0..31 or 32..63
    const int cofs  = (wave < 2) ? 0 : 32;
    f32x4 acc[2][2];
#pragma unroll
    for (int mt = 0; mt < 2; ++mt)
#pragma unroll
      for (int nt = 0; nt < 2; ++nt) acc[mt][nt] = fzero;
#pragma unroll
    for (int k0 = 0; k0 < 256; k0 += 32) {
      bf16x8 a0 = *(const bf16x8*)&xsf[xs_i(mbase + l15, k0 + g * 8)];
      bf16x8 a1 = *(const bf16x8*)&xsf[xs_i(mbase + 16 + l15, k0 + g * 8)];
      bf16x8 b0 = *(const bf16x8*)(wt + l15 * 256 + k0 + g * 8);
      bf16x8 b1 = *(const bf16x8*)(wt + (16 + l15) * 256 + k0 + g * 8);
      acc[0][0] = MFMA16(a0, b0, acc[0][0]);
      acc[0][1] = MFMA16(a0, b1, acc[0][1]);
      acc[1][0] = MFMA16(a1, b0, acc[1][0]);
      acc[1][1] = MFMA16(a1, b1, acc[1][1]);
    }
    const bool isQ = (wave < 2);
#pragma unroll
    for (int nt = 0; nt < 2; ++nt) {
      const int coln = (nt << 4) + l15;
      const float bval = (coln < kNCLS) ? bias[coln] : 0.f;
#pragma unroll
      for (int mt = 0; mt < 2; ++mt) {
#pragma unroll
        for (int r = 0; r < 4; ++r) {
          const int row = mbase + (mt << 4) + (g << 2) + r;  // token
          const float v = acc[mt][nt][r] + bval;
          sbf[sb_i(row, cofs + coln)] = (bf16_t)v;
          if (isQ && coln < kNCLS) {
            out0[(size_t)(pixbase + ((row >> 3) << 8) + (row & 7)) * kNCLS + coln] = v;
          }
        }
      }
    }
  }
  BAR();

  // ---- phase S: S = Q K^T (64x64, K=32 padded), in-register softmax -> Ps ----
  {
    const int mbase = wave << 4;
    const bf16x8 aq = *(const bf16x8*)&sbf[sb_i(mbase + l15, g * 8)];
    f32x4 s[4];
#pragma unroll
    for (int nt = 0; nt < 4; ++nt) {
      bf16x8 bk8 = *(const bf16x8*)&sbf[sb_i((nt << 4) + l15, 32 + g * 8)];
      s[nt] = MFMA16(aq, bk8, fzero);
    }
    BAR();  // all waves done reading Q/K (Ps aliases them)
#pragma unroll
    for (int r = 0; r < 4; ++r) {
      float m = fmaxf(fmaxf(s[0][r], s[1][r]), fmaxf(s[2][r], s[3][r]));
#pragma unroll
      for (int off = 1; off < 16; off <<= 1) m = fmaxf(m, __shfl_xor(m, off));
      float e0 = __expf(s[0][r] - m), e1 = __expf(s[1][r] - m);
      float e2 = __expf(s[2][r] - m), e3 = __expf(s[3][r] - m);
      float sum = (e0 + e1) + (e2 + e3);
#pragma unroll
      for (int off = 1; off < 16; off <<= 1) sum += __shfl_xor(sum, off);
      const float inv = 1.0f / sum;
      const int row = mbase + (g << 2) + r;
      sbf[sb_i(row, l15)]      = (bf16_t)(e0 * inv);
      sbf[sb_i(row, 16 + l15)] = (bf16_t)(e1 * inv);
      sbf[sb_i(row, 32 + l15)] = (bf16_t)(e2 * inv);
      sbf[sb_i(row, 48 + l15)] = (bf16_t)(e3 * inv);
    }
  }
  BAR();  // P visible to all waves

  // ---- hoist P fragments to registers ----
  bf16x8 bp[4][2];
#pragma unroll
  for (int nt = 0; nt < 4; ++nt) {
    bp[nt][0] = *(const bf16x8*)&sbf[sb_i((nt << 4) + l15, g * 8)];
    bp[nt][1] = *(const bf16x8*)&sbf[sb_i((nt << 4) + l15, 32 + g * 8)];
  }
  BAR();  // Ps reads done before Utc (same buffer) is overwritten
  // ---- tail: wave w owns out1 channels [w*64,(w+1)*64) = lines 2w,2w+1 ----
  // Private Utc slice = sbf rows [w*16,w*16+16). Pass p -> line p, accU[2][4]
  // (32 f32) only. BARs below are RENDEZVOUS-ONLY (no cross-wave data dep):
  // they bound wave drift, which empirically governs HBM write cleanliness.

#pragma unroll
  for (int p = 0; p < 2; ++p) {
    // ---- U sweep for this line: U^T[w*64+p*32 .. +32)[all 64 tokens] ----
    f32x4 accU[2][4];  // [ctl][mt]
#pragma unroll
    for (int ctl = 0; ctl < 2; ++ctl)
#pragma unroll
      for (int mt = 0; mt < 4; ++mt) accU[ctl][mt] = fzero;
    {
      const bf16_t* wftp = wsb + WFT_OFF + (size_t)((wave << 6) + (p << 5) + l15) * 256;
#pragma unroll
      for (int k0 = 0; k0 < 256; k0 += 32) {
        bf16x8 af0 = *(const bf16x8*)&xsf[xs_i(l15, k0 + g * 8)];
        bf16x8 af1 = *(const bf16x8*)&xsf[xs_i(16 + l15, k0 + g * 8)];
        bf16x8 af2 = *(const bf16x8*)&xsf[xs_i(32 + l15, k0 + g * 8)];
        bf16x8 af3 = *(const bf16x8*)&xsf[xs_i(48 + l15, k0 + g * 8)];
        bf16x8 bf0 = *(const bf16x8*)(wftp + k0 + g * 8);
        bf16x8 bf1 = *(const bf16x8*)(wftp + 16 * 256 + k0 + g * 8);
        accU[0][0] = MFMA16(af0, bf0, accU[0][0]);
        accU[0][1] = MFMA16(af1, bf0, accU[0][1]);
        accU[0][2] = MFMA16(af2, bf0, accU[0][2]);
        accU[0][3] = MFMA16(af3, bf0, accU[0][3]);
        accU[1][0] = MFMA16(af0, bf1, accU[1][0]);
        accU[1][1] = MFMA16(af1, bf1, accU[1][1]);
        accU[1][2] = MFMA16(af2, bf1, accU[1][2]);
        accU[1][3] = MFMA16(af3, bf1, accU[1][3]);
      }
    }
    BAR();  // rendezvous: keep waves phase-aligned entering the store phase

    // ---- bounce both ct tiles through private slice -> A-frags ----
    bf16x8 av[2][2];  // [ctl][khalf]
#pragma unroll
    for (int ctl = 0; ctl < 2; ++ctl) {
#pragma unroll
      for (int mt = 0; mt < 4; ++mt) {
        bf16x4 pk;
#pragma unroll
        for (int r = 0; r < 4; ++r) pk[r] = (bf16_t)accU[ctl][mt][r];
        *(bf16x4*)&sbf[sb_i((wave << 4) + l15, (mt << 4) + (g << 2))] = pk;
      }
      av[ctl][0] = *(const bf16x8*)&sbf[sb_i((wave << 4) + l15, g * 8)];
      av[ctl][1] = *(const bf16x8*)&sbf[sb_i((wave << 4) + l15, 32 + g * 8)];
    }

    // ---- PV + fused epilogue, line-complete o0/o1 store pairs ----
    const int c2 = (wave << 6) + (p << 5) + (g << 2);
    const f32x4 bfv0 = *(const f32x4*)(bff + c2);
    const f32x4 bfv1 = *(const f32x4*)(bff + c2 + 16);
#pragma unroll
    for (int nt = 0; nt < 4; ++nt) {
      f32x4 a0 = MFMA16(av[0][0], bp[nt][0], fzero);
      a0 = MFMA16(av[0][1], bp[nt][1], a0);
      f32x4 a1 = MFMA16(av[1][0], bp[nt][0], fzero);
      a1 = MFMA16(av[1][1], bp[nt][1], a1);
      const int t = (nt << 4) + l15;
      const bf16x4 xv0 = *(const bf16x4*)&xsf[xs_i(t, c2)];
      const bf16x4 xv1 = *(const bf16x4*)&xsf[xs_i(t, c2 + 16)];
      f32x4 o0, o1;
#pragma unroll
      for (int r = 0; r < 4; ++r) {
        o0[r] = gm * (a0[r] + bfv0[r]) + (float)xv0[r];
        o1[r] = gm * (a1[r] + bfv1[r]) + (float)xv1[r];
      }
      float* dst = out1 + (size_t)(pixbase + ((t >> 3) << 8) + (t & 7)) * kC + c2;
      *(f32x4*)dst = o0;          // bytes [g*16, g*16+16) of line half 0
      *(f32x4*)(dst + 16) = o1;   // bytes [64+g*16, ...) — full 128B line
    }
    BAR();  // rendezvous: bound drift across passes
  }
}

extern "C" void kernel_launch(void* const* d_in, const int* in_sizes, int n_in,
                              void* d_out, int out_size, void* d_ws, size_t ws_size,
                              hipStream_t stream)
{
  const float* x     = (const float*)d_in[0];
  const float* Wq    = (const float*)d_in[1];
  const float* bq    = (const float*)d_in[2];
  const float* Wk    = (const float*)d_in[3];
  const float* bk    = (const float*)d_in[4];
  const float* Wv    = (const float*)d_in[5];
  const float* bv    = (const float*)d_in[6];
  const float* Wres  = (const float*)d_in[7];
  const float* bres  = (const float*)d_in[8];
  const float* gamma = (const float*)d_in[9];
  bf16_t* wsb = (bf16_t*)d_ws;                         // 81920 bf16 = 163840 B
  float*  bff = (float*)((char*)d_ws + BF_BYTE_OFF);   // + 1024 B
  float* out0 = (float*)d_out;                         // (8,256,256,18)
  float* out1 = out0 + (size_t)8 * 256 * 256 * 18;     // (8,256,256,256)

  prep_kernel<<<dim3(321), dim3(256), 0, stream>>>(Wq, Wk, Wv, bv, Wres, bres, wsb, bff);
  semwin_main<<<dim3(8192), dim3(256), 0, stream>>>(x, bq, bk, gamma, wsb, bff, out0, out1);
}